// Round 7
// baseline (208.091 us; speedup 1.0000x reference)
//
#include <hip/hip_runtime.h>
#include <stdint.h>
#include <limits.h>

// ---------------------------------------------------------------------------
// RPN loss, replication of the JAX reference (incl. threefry PRNG).
// Round 15: single kernel + cheaper division.
//  - r14 facts: glue is ~70us FIXED (not per-boundary); kernel time is the
//    lever (was: memset 2 + iou 57 + loss2 ~14). Harness compares at bf16
//    granularity (thr 1.6e-2): summation order is free; selection decisions
//    tolerate ~ulp-level div deviation (each flip ~1e-3 on output).
//  - div: v_rcp_f32 + 1 Newton + mul (4 ops) instead of IEEE div (~10 ops).
//    EXACT_DIV switch kept for fallback.
//  - area_g precomputed in LDS (b128 gbox + b32 garea: still 2 DS reads/iter,
//    -3 VALU/iter).
//  - K2 folded into the per-image tail (proven r13/r14 ticket+sc1 mechanism):
//    tail = force -> cutoff -> scan image (agent loads) -> LDS keep/cand
//    lists -> rank -> loss -> bsums; 9th ticket does the final combine.
//    Kept anchors per image = tp+tn <= 256 (provable list bounds).
// ---------------------------------------------------------------------------
#define PARTITIONABLE 1
#define EXACT_DIV 0

#define B_ 8
#define K_ 9
#define H_ 64
#define W_ 64
#define G_ 128
#define A_ 36864            // K*H*W
#define HALF_A 18432
#define NBUCK 1024          // buckets over 23-bit v (v>>13)
#define BSHIFT 13
#define CCAP 256            // cutoff-bucket candidates per row (expect ~35)
#define KCAP 320            // kept anchors per image (hard bound 256)
#define NLAB  1152          // (A_/256) * B_
#define NPB   144           // blocks per image = A_/256

struct KeyParams { uint32_t k[B_][4]; };   // per image: k1.(0,1), k2.(0,1)

__host__ __device__ static inline uint32_t rotl32(uint32_t x, int r) {
  return (x << r) | (x >> (32 - r));
}

// JAX threefry2x32: 20 rounds, key injections every 4 rounds.
__host__ __device__ static inline void tf2x32(uint32_t k0, uint32_t k1,
                                              uint32_t x0, uint32_t x1,
                                              uint32_t& o0, uint32_t& o1) {
  uint32_t ks2 = k0 ^ k1 ^ 0x1BD11BDAu;
  x0 += k0; x1 += k1;
#define TF_R(r) { x0 += x1; x1 = rotl32(x1, r); x1 ^= x0; }
  TF_R(13) TF_R(15) TF_R(26) TF_R(6)
  x0 += k1;  x1 += ks2 + 1u;
  TF_R(17) TF_R(29) TF_R(16) TF_R(24)
  x0 += ks2; x1 += k0 + 2u;
  TF_R(13) TF_R(15) TF_R(26) TF_R(6)
  x0 += k0;  x1 += k1 + 3u;
  TF_R(17) TF_R(29) TF_R(16) TF_R(24)
  x0 += k1;  x1 += ks2 + 4u;
  TF_R(13) TF_R(15) TF_R(26) TF_R(6)
  x0 += ks2; x1 += k0 + 5u;
#undef TF_R
  o0 = x0; o1 = x1;
}

__device__ static inline uint32_t anchor_vbits(uint32_t k0, uint32_t k1, int a) {
  uint32_t o0, o1;
#if PARTITIONABLE
  tf2x32(k0, k1, 0u, (uint32_t)a, o0, o1);
  return (o0 ^ o1) >> 9;
#else
  if (a < HALF_A) { tf2x32(k0, k1, (uint32_t)a, (uint32_t)(a + HALF_A), o0, o1); return o0 >> 9; }
  else            { tf2x32(k0, k1, (uint32_t)(a - HALF_A), (uint32_t)a, o0, o1); return o1 >> 9; }
#endif
}

__device__ static inline float area_of(float x0, float y0, float x1, float y1) {
#pragma clang fp contract(off)
  return (x1 - x0) * (y1 - y0);
}

__device__ static inline void encode4(float4 an, float4 gg, float* tt) {
#pragma clang fp contract(off)
  float aw  = an.z - an.x,            ah  = an.w - an.y;
  float acx = (an.x + an.z) * 0.5f,   acy = (an.y + an.w) * 0.5f;
  float gw  = gg.z - gg.x,            gh  = gg.w - gg.y;
  float gcx = (gg.x + gg.z) * 0.5f,   gcy = (gg.y + gg.w) * 0.5f;
  tt[0] = (gcx - acx) / aw;
  tt[1] = (gcy - acy) / ah;
  tt[2] = logf(gw / aw);
  tt[3] = logf(gh / ah);
}

__device__ static inline int block_reduce_int(int v, int* sh) {
  int t = threadIdx.x;
  sh[t] = v; __syncthreads();
  for (int s = 128; s > 0; s >>= 1) { if (t < s) sh[t] += sh[t + s]; __syncthreads(); }
  int r = sh[0]; __syncthreads();
  return r;
}
__device__ static inline float block_reduce_float(float v, float* sh) {
  int t = threadIdx.x;
  sh[t] = v; __syncthreads();
  for (int s = 128; s > 0; s >>= 1) { if (t < s) sh[t] += sh[t + s]; __syncthreads(); }
  float r = sh[0]; __syncthreads();
  return r;
}

// Agent-scope (LLC-direct) relaxed stores/loads: plain-store cost, no cache
// maintenance ops. For data a cross-XCD tail block reads within the kernel.
__device__ static inline void st_agent_i32(int* p, int v) {
  __hip_atomic_store(p, v, __ATOMIC_RELAXED, __HIP_MEMORY_SCOPE_AGENT);
}
__device__ static inline void st_agent_u32(uint32_t* p, uint32_t v) {
  __hip_atomic_store(p, v, __ATOMIC_RELAXED, __HIP_MEMORY_SCOPE_AGENT);
}
__device__ static inline int ld_agent_i32(const int* p) {
  return __hip_atomic_load(p, __ATOMIC_RELAXED, __HIP_MEMORY_SCOPE_AGENT);
}
__device__ static inline uint32_t ld_agent_u32(const uint32_t* p) {
  return __hip_atomic_load(p, __ATOMIC_RELAXED, __HIP_MEMORY_SCOPE_AGENT);
}
__device__ static inline unsigned long long ld_agent_u64(const unsigned long long* p) {
  return __hip_atomic_load(p, __ATOMIC_RELAXED, __HIP_MEMORY_SCOPE_AGENT);
}
__device__ static inline float ld_agent_f32(const float* p) {
  return __hip_atomic_load(p, __ATOMIC_RELAXED, __HIP_MEMORY_SCOPE_AGENT);
}

// ---------------------------------------------------------------------------
// The single kernel. Grid = NLAB x 256.
// ---------------------------------------------------------------------------
__global__ __launch_bounds__(256) void mega2_k(
    const float* __restrict__ anchors, const float* __restrict__ gtb,
    const float* __restrict__ cls, const float* __restrict__ boxp,
    int* __restrict__ labels, int* __restrict__ mgt,
    uint32_t* __restrict__ vpos, uint32_t* __restrict__ vneg,
    int* __restrict__ ghist, int* __restrict__ counts,
    unsigned long long* __restrict__ gmax,
    int* __restrict__ targets, float* __restrict__ bsums,
    int* __restrict__ tickets, float* __restrict__ out, KeyParams kp) {
  __shared__ float4 gbox[2 * G_];               // gt boxes, duplicated
  __shared__ float  garea[2 * G_];              // gt areas, duplicated
  __shared__ unsigned long long slot2[2 * G_];  // per-(block,g residue) max pack
  __shared__ int red[256];
  __shared__ int sup[16];
  __shared__ int last;
  // tail state
  __shared__ int tcb[2], tR[2], ttp[2];
  __shared__ int nkeep, ncand[2];
  __shared__ uint32_t cv[2][CCAP];
  __shared__ int      ca[2][CCAP];
  __shared__ int      keepA[KCAP];
  __shared__ float redf[256];

  const int bid = blockIdx.x;
  const int t = threadIdx.x;
  const int b  = bid / NPB;
  const int xb = bid % NPB;
  const int a  = xb * 256 + t;                   // < A_ exactly
  const size_t idx = (size_t)b * A_ + a;

  // ========== body: IoU + labels + PRNG + hist + counts ===================
  {
    if (t < G_) {
      float4 gg = ((const float4*)gtb)[b * G_ + t];
      gbox[t] = gg; gbox[t + G_] = gg;
      float ag = area_of(gg.x, gg.y, gg.z, gg.w);
      garea[t] = ag; garea[t + G_] = ag;
    }
    slot2[t] = 0ull;                             // covers all 256 residues
    __syncthreads();

    float4 an = ((const float4*)anchors)[a];
    float area_a = area_of(an.x, an.y, an.z, an.w);
    const int t7 = t & (G_ - 1);
    const unsigned long long alow = (unsigned long long)(~(uint32_t)a);
    unsigned long long blp = 0ull;               // (q_bits<<32 | g^127) max
#pragma unroll 4
    for (int s = 0; s < G_; s++) {
      const int gi = t7 + s;                     // in [0, 254]; g = gi & 127
      float4 gg = gbox[gi];
      float ag  = garea[gi];
      float q;
      {
#pragma clang fp contract(off)
        float ltx = fmaxf(an.x, gg.x), lty = fmaxf(an.y, gg.y);
        float rbx = fminf(an.z, gg.z), rby = fminf(an.w, gg.w);
        float w = rbx - ltx; w = (w < 0.f) ? 0.f : w;
        float h = rby - lty; h = (h < 0.f) ? 0.f : h;
        float inter = w * h;
        float denom = area_a + ag - inter + 1e-6f;
#if EXACT_DIV
        q = inter / denom;
#else
        float r0 = __builtin_amdgcn_rcpf(denom);
        float r1 = r0 * __builtin_fmaf(-denom, r0, 2.0f);   // 1 Newton step
        q = inter * r1;                                      // <~1.5 ulp of IEEE
#endif
      }
      unsigned long long hi = (unsigned long long)__float_as_uint(q) << 32;
      unsigned long long lp = hi | (unsigned)((gi & (G_ - 1)) ^ (G_ - 1));
      if (lp > blp) blp = lp;                    // (higher iou, then smaller g)
      atomicMax(&slot2[gi], hi | alow);          // fire-and-forget, lanes distinct
    }
    __syncthreads();
    if (t < G_) {
      unsigned long long p = slot2[t];
      unsigned long long q2 = slot2[t + G_];
      if (q2 > p) p = q2;
      atomicMax(&gmax[b * G_ + t], p);           // once per (block, g)
    }

    float bv = __uint_as_float((uint32_t)(blp >> 32));
    int   bi = ((int)(blp & (unsigned long long)(G_ - 1))) ^ (G_ - 1);
    int lb = (bv < 0.3f) ? 0 : ((bv >= 0.7f) ? 1 : -1);
    uint32_t vp = anchor_vbits(kp.k[b][0], kp.k[b][1], a);
    uint32_t vn = anchor_vbits(kp.k[b][2], kp.k[b][3], a);
    st_agent_i32(&labels[idx], lb);    // LLC-direct: tail reads cross-XCD
    st_agent_u32(&vpos[idx], vp);
    st_agent_u32(&vneg[idx], vn);
    st_agent_i32(&mgt[idx], bi);
    if (lb == 1)      atomicAdd(&ghist[(b * 2 + 0) * NBUCK + (vp >> BSHIFT)], 1);
    else if (lb == 0) atomicAdd(&ghist[(b * 2 + 1) * NBUCK + (vn >> BSHIFT)], 1);
    int packed = (lb == 1 ? 1 : 0) | ((lb == 0 ? 1 : 0) << 16);
    int rr = block_reduce_int(packed, red);
    if (t == 0) {
      atomicAdd(&counts[b * 2 + 0], rr & 0xFFFF);
      atomicAdd(&counts[b * 2 + 1], rr >> 16);
    }
  }

  // ---- per-image ticket: syncthreads drains vmcnt (stores acked at LLC) --
  __syncthreads();
  if (t == 0) {
    int v = __hip_atomic_fetch_add(&tickets[b], 1, __ATOMIC_RELAXED,
                                   __HIP_MEMORY_SCOPE_AGENT);
    last = (v == NPB - 1);
    nkeep = 0; ncand[0] = 0; ncand[1] = 0;
  }
  __syncthreads();
  if (!last) return;

  // ========== tail: force best anchor per gt ==============================
  if (t < G_) {
    unsigned long long gm = ld_agent_u64(&gmax[b * G_ + t]);
    int fa = (int)(~(uint32_t)(gm & 0xFFFFFFFFull));
    size_t fidx = (size_t)b * A_ + fa;
    int old = atomicExch(&labels[fidx], 1);
    if (old != 1) {
      atomicAdd(&counts[b * 2 + 0], 1);
      atomicAdd(&ghist[(b * 2 + 0) * NBUCK + (ld_agent_u32(&vpos[fidx]) >> BSHIFT)], 1);
      if (old == 0) {
        atomicSub(&counts[b * 2 + 1], 1);
        atomicSub(&ghist[(b * 2 + 1) * NBUCK + (ld_agent_u32(&vneg[fidx]) >> BSHIFT)], 1);
      }
    }
  }
  __syncthreads();   // drain force atomics before counts/ghist reads

  // ========== tail: cutoff bucket + remainder (2 rows) ====================
  {
    int npos = ld_agent_i32(&counts[b * 2 + 0]);
    int nneg = ld_agent_i32(&counts[b * 2 + 1]);
    int tp = npos < 128 ? npos : 128;
    int tn = 256 - tp; if (nneg < tn) tn = nneg;
    for (int c = 0; c < 2; ++c) {
      const int row = b * 2 + c;
      const int target = (c == 0) ? tp : tn;
      const int* hist = ghist + (size_t)row * NBUCK;
      { int s = 0; const int base = t * 4;
        for (int i = 0; i < 4; i++) s += ld_agent_i32(&hist[base + i]);
        red[t] = s; }
      __syncthreads();
      if (t < 16) { int ss = 0; for (int j = 0; j < 16; j++) ss += red[t * 16 + j]; sup[t] = ss; }
      __syncthreads();
      if (t == 0) {
        int cb = INT_MAX, R = 0;
        if (target > 0) {
          int cum = 0, si = 0;
          for (int i = 15; i >= 0; i--) { if (cum + sup[i] >= target) { si = i; break; } cum += sup[i]; }
          int sj = si * 16;
          for (int j = si * 16 + 15; j >= si * 16; j--) { if (cum + red[j] >= target) { sj = j; break; } cum += red[j]; }
          for (int k = sj * 4 + 3; k >= sj * 4; k--) {
            int hv = ld_agent_i32(&hist[k]);
            if (cum + hv >= target) { cb = k; R = target - cum; break; }
            cum += hv;
          }
        }
        tcb[c] = cb; tR[c] = R; ttp[c] = target;
        st_agent_i32(&targets[row], target);
      }
      __syncthreads();
    }
  }

  // ========== tail: scan image, collect kept + candidates =================
  {
    const int cb0 = tcb[0], cb1 = tcb[1];
    for (int i = t; i < A_; i += 256) {
      size_t ii = (size_t)b * A_ + i;
      int lb = ld_agent_i32(&labels[ii]);
      if (lb < 0) continue;
      int c = (lb == 1) ? 0 : 1;
      uint32_t v = ld_agent_u32(c == 0 ? &vpos[ii] : &vneg[ii]);
      int bk = (int)(v >> BSHIFT);
      int cb = (c == 0) ? cb0 : cb1;
      if (bk > cb) {
        int p = atomicAdd(&nkeep, 1);
        if (p < KCAP) keepA[p] = i | (c << 16);
      } else if (bk == cb) {
        int p = atomicAdd(&ncand[c], 1);
        if (p < CCAP) { cv[c][p] = v; ca[c][p] = i; }
      }
    }
    __syncthreads();
    // rank candidates; kept ones join the keep list
    for (int c = 0; c < 2; ++c) {
      int n = ncand[c]; if (n > CCAP) n = CCAP;
      const int R = tR[c];
      for (int j = t; j < n; j += 256) {
        uint32_t v = cv[c][j]; int a2 = ca[c][j];
        int r = 0;
        for (int k2 = 0; k2 < n; k2++) {
          uint32_t vk = cv[c][k2];
          if (vk > v || (vk == v && ca[c][k2] < a2)) r++;
        }
        if (r < R) {
          int p = atomicAdd(&nkeep, 1);
          if (p < KCAP) keepA[p] = a2 | (c << 16);
        }
      }
    }
    __syncthreads();
  }

  // ========== tail: loss over kept anchors ================================
  {
    int nk = nkeep; if (nk > KCAP) nk = KCAP;
    float sb = 0.f, ss = 0.f;
    for (int j = t; j < nk; j += 256) {
      int e = keepA[j];
      int a2 = e & 0xFFFF;
      bool pos = ((e >> 16) == 0);
      int kk = a2 % K_; int hw = a2 / K_; int hh = hw / W_; int wx = hw % W_;
      float x = cls[(((size_t)b * K_ + kk) * H_ + hh) * W_ + wx];
      float sp = fmaxf(x, 0.f) + log1pf(expf(-fabsf(x)));   // logaddexp(x,0)
      sb += pos ? (sp - x) : sp;
      if (pos) {
        float4 an = ((const float4*)anchors)[a2];
        int mg = ld_agent_i32(&mgt[(size_t)b * A_ + a2]);
        float4 gg = ((const float4*)gtb)[b * G_ + mg];
        float tt[4]; encode4(an, gg, tt);
        for (int cc2 = 0; cc2 < 4; cc2++) {
          float p = boxp[(((size_t)b * (4 * K_) + (4 * kk + cc2)) * H_ + hh) * W_ + wx];
          float d = p - tt[cc2];
          float ad = fabsf(d);
          ss += (ad < 1.f) ? (0.5f * d * d) : (ad - 0.5f);
        }
      }
    }
    float sbT = block_reduce_float(sb, redf);
    float ssT = block_reduce_float(ss, redf);
    if (t == 0) {
      if (sbT != 0.f) atomicAdd(&bsums[b * 2 + 0], sbT);
      if (ssT != 0.f) atomicAdd(&bsums[b * 2 + 1], ssT);
    }
  }

  // ---- final ticket: 8 arrivals, one per image tail ----------------------
  __syncthreads();   // drain bsums atomics + targets stores
  if (t == 0) {
    int v = __hip_atomic_fetch_add(&tickets[B_], 1, __ATOMIC_RELAXED,
                                   __HIP_MEMORY_SCOPE_AGENT);
    last = (v == B_ - 1);
  }
  __syncthreads();
  if (!last) return;

  if (t == 0) {
    float cl = 0.f, bl = 0.f;
    for (int bb = 0; bb < B_; bb++) {
      int tpv = ld_agent_i32(&targets[bb * 2 + 0]);
      int tnv = ld_agent_i32(&targets[bb * 2 + 1]);
      float s0 = ld_agent_f32(&bsums[bb * 2 + 0]);
      float s1 = ld_agent_f32(&bsums[bb * 2 + 1]);
      cl += s0 / fmaxf((float)(tpv + tnv), 1.f);
      bl += s1 / fmaxf(4.f * (float)tpv, 1.f);
    }
    cl *= 0.125f; bl *= 0.125f;
    out[0] = cl; out[1] = bl; out[2] = cl + bl;
  }
}

static void compute_keys(KeyParams& kp) {
  const uint32_t r0 = 0u, r1 = 42u;        // jax.random.key(42) -> (hi, lo)
#if PARTITIONABLE
  for (int b = 0; b < B_; b++) {
    uint32_t kb0, kb1;
    tf2x32(r0, r1, 0u, (uint32_t)b, kb0, kb1);        // split(root, 8)[b]
    uint32_t a0, a1, c0, c1;
    tf2x32(kb0, kb1, 0u, 0u, a0, a1);                 // split(key)[0] = k1
    tf2x32(kb0, kb1, 0u, 1u, c0, c1);                 // split(key)[1] = k2
    kp.k[b][0] = a0; kp.k[b][1] = a1; kp.k[b][2] = c0; kp.k[b][3] = c1;
  }
#else
  uint32_t o0[8], o1[8], flat[16];
  for (int i = 0; i < 8; i++) tf2x32(r0, r1, (uint32_t)i, (uint32_t)(8 + i), o0[i], o1[i]);
  for (int i = 0; i < 8; i++) { flat[i] = o0[i]; flat[8 + i] = o1[i]; }
  for (int b = 0; b < B_; b++) {
    uint32_t kb0 = flat[2 * b], kb1 = flat[2 * b + 1];
    uint32_t a0, b0, a1, b1;
    tf2x32(kb0, kb1, 0u, 2u, a0, b0);
    tf2x32(kb0, kb1, 1u, 3u, a1, b1);
    kp.k[b][0] = a0; kp.k[b][1] = a1; kp.k[b][2] = b0; kp.k[b][3] = b1;
  }
#endif
}

extern "C" void kernel_launch(void* const* d_in, const int* in_sizes, int n_in,
                              void* d_out, int out_size, void* d_ws, size_t ws_size,
                              hipStream_t stream) {
  const float* cls     = (const float*)d_in[0];   // [B,K,H,W]
  const float* boxp    = (const float*)d_in[1];   // [B,4K,H,W]
  const float* anchors = (const float*)d_in[2];   // [A,4]
  const float* gtb     = (const float*)d_in[3];   // [B,G,4]
  float* out = (float*)d_out;

  uint8_t* w = (uint8_t*)d_ws;
  // zeroed region [0, 74240): gmax + ghist + counts + bsums + tickets
  unsigned long long* gmax = (unsigned long long*)w;    // B*G u64 (8 KB)
  int*      ghist   = (int*)(w + 8192);                 // 16*NBUCK ints (64 KB)
  int*      counts  = (int*)(w + 73728);                // 16 ints (pad 128)
  float*    bsums   = (float*)(w + 73856);              // 16 floats (pad 128)
  int*      tickets = (int*)(w + 73984);                // 9 ints (pad 256)
  // non-zeroed region
  int*      labels  = (int*)(w + 74240);                // B*A
  int*      mgt     = labels + (size_t)B_ * A_;         // B*A
  uint32_t* vpos    = (uint32_t*)(mgt + (size_t)B_ * A_);  // B*A
  uint32_t* vneg    = vpos + (size_t)B_ * A_;           // B*A
  int*      targets = (int*)(vneg + (size_t)B_ * A_);   // 16

  KeyParams kp;
  compute_keys(kp);

  (void)hipMemsetAsync(w, 0, 74240, stream);
  mega2_k<<<NLAB, 256, 0, stream>>>(anchors, gtb, cls, boxp, labels, mgt,
                                    vpos, vneg, ghist, counts, gmax,
                                    targets, bsums, tickets, out, kp);
}

// Round 9
// 191.743 us; speedup vs baseline: 1.0853x; 1.0853x over previous
//
#include <hip/hip_runtime.h>
#include <stdint.h>
#include <limits.h>

// ---------------------------------------------------------------------------
// RPN loss, replication of the JAX reference (incl. threefry PRNG).
// Round 17 == Round 16 resubmitted verbatim (r16 got "container failed
// twice" -- infra error, no test verdict; audit found no hang/OOB mechanism;
// same precedent as r12->r13 which then passed).
//
// Design (r16): r14's proven 2-dispatch structure (body grid-wide, O(small)
// per-image tails; r15's O(A) single-block tail scan was the 120us bug),
// plus all validated trims:
//  - ONE packed u64 sc1 store per anchor: {v:23|mgt:7|lb+1:2|...|forced:63}.
//    Body computes only the needed threefry (vp if lb!=0 else vn).
//  - force = atomicOr(bit63) on the pack: old label+v in one LLC RMW;
//    vp recomputed only for oldlb==0 forced anchors (<=128/image).
//  - ballot/popcount wave counts (no 9-barrier block reduce in body).
//  - fast div rcp+Newton (r15: absmax 0.0), gbox+garea in LDS.
//  - K2: grid-wide pack scan (1 load/anchor) + LDS-staged rank tail + final.
// ---------------------------------------------------------------------------
#define PARTITIONABLE 1

#define B_ 8
#define K_ 9
#define H_ 64
#define W_ 64
#define G_ 128
#define A_ 36864            // K*H*W
#define HALF_A 18432
#define NBUCK 1024          // buckets over 23-bit v (v>>13)
#define BSHIFT 13
#define VMASK 0x7FFFFFu
#define CCAP 256            // cutoff-bucket candidates per row (expect ~30)
#define NLAB  1152          // (A_/256) * B_
#define NPB   144           // blocks per image = A_/256

struct KeyParams { uint32_t k[B_][4]; };   // per image: k1.(0,1), k2.(0,1)

__host__ __device__ static inline uint32_t rotl32(uint32_t x, int r) {
  return (x << r) | (x >> (32 - r));
}

// JAX threefry2x32: 20 rounds, key injections every 4 rounds.
__host__ __device__ static inline void tf2x32(uint32_t k0, uint32_t k1,
                                              uint32_t x0, uint32_t x1,
                                              uint32_t& o0, uint32_t& o1) {
  uint32_t ks2 = k0 ^ k1 ^ 0x1BD11BDAu;
  x0 += k0; x1 += k1;
#define TF_R(r) { x0 += x1; x1 = rotl32(x1, r); x1 ^= x0; }
  TF_R(13) TF_R(15) TF_R(26) TF_R(6)
  x0 += k1;  x1 += ks2 + 1u;
  TF_R(17) TF_R(29) TF_R(16) TF_R(24)
  x0 += ks2; x1 += k0 + 2u;
  TF_R(13) TF_R(15) TF_R(26) TF_R(6)
  x0 += k0;  x1 += k1 + 3u;
  TF_R(17) TF_R(29) TF_R(16) TF_R(24)
  x0 += k1;  x1 += ks2 + 4u;
  TF_R(13) TF_R(15) TF_R(26) TF_R(6)
  x0 += ks2; x1 += k0 + 5u;
#undef TF_R
  o0 = x0; o1 = x1;
}

__device__ static inline uint32_t anchor_vbits(uint32_t k0, uint32_t k1, int a) {
  uint32_t o0, o1;
#if PARTITIONABLE
  tf2x32(k0, k1, 0u, (uint32_t)a, o0, o1);
  return (o0 ^ o1) >> 9;
#else
  if (a < HALF_A) { tf2x32(k0, k1, (uint32_t)a, (uint32_t)(a + HALF_A), o0, o1); return o0 >> 9; }
  else            { tf2x32(k0, k1, (uint32_t)(a - HALF_A), (uint32_t)a, o0, o1); return o1 >> 9; }
#endif
}

__device__ static inline float area_of(float x0, float y0, float x1, float y1) {
#pragma clang fp contract(off)
  return (x1 - x0) * (y1 - y0);
}

__device__ static inline void encode4(float4 an, float4 gg, float* tt) {
#pragma clang fp contract(off)
  float aw  = an.z - an.x,            ah  = an.w - an.y;
  float acx = (an.x + an.z) * 0.5f,   acy = (an.y + an.w) * 0.5f;
  float gw  = gg.z - gg.x,            gh  = gg.w - gg.y;
  float gcx = (gg.x + gg.z) * 0.5f,   gcy = (gg.y + gg.w) * 0.5f;
  tt[0] = (gcx - acx) / aw;
  tt[1] = (gcy - acy) / ah;
  tt[2] = logf(gw / aw);
  tt[3] = logf(gh / ah);
}

__device__ static inline float block_reduce_float(float v, float* sh) {
  int t = threadIdx.x;
  sh[t] = v; __syncthreads();
  for (int s = 128; s > 0; s >>= 1) { if (t < s) sh[t] += sh[t + s]; __syncthreads(); }
  float r = sh[0]; __syncthreads();
  return r;
}

// Agent-scope (LLC-direct) relaxed ops: plain-store cost, no cache-maint ops.
__device__ static inline void st_agent_u64(unsigned long long* p, unsigned long long v) {
  __hip_atomic_store(p, v, __ATOMIC_RELAXED, __HIP_MEMORY_SCOPE_AGENT);
}
__device__ static inline void st_agent_i32(int* p, int v) {
  __hip_atomic_store(p, v, __ATOMIC_RELAXED, __HIP_MEMORY_SCOPE_AGENT);
}
__device__ static inline void st_agent_u32(uint32_t* p, uint32_t v) {
  __hip_atomic_store(p, v, __ATOMIC_RELAXED, __HIP_MEMORY_SCOPE_AGENT);
}
__device__ static inline int ld_agent_i32(const int* p) {
  return __hip_atomic_load(p, __ATOMIC_RELAXED, __HIP_MEMORY_SCOPE_AGENT);
}
__device__ static inline uint32_t ld_agent_u32(const uint32_t* p) {
  return __hip_atomic_load(p, __ATOMIC_RELAXED, __HIP_MEMORY_SCOPE_AGENT);
}
__device__ static inline unsigned long long ld_agent_u64(const unsigned long long* p) {
  return __hip_atomic_load(p, __ATOMIC_RELAXED, __HIP_MEMORY_SCOPE_AGENT);
}
__device__ static inline float ld_agent_f32(const float* p) {
  return __hip_atomic_load(p, __ATOMIC_RELAXED, __HIP_MEMORY_SCOPE_AGENT);
}

// ---------------------------------------------------------------------------
// K1: IoU body (all blocks) + per-image tail {force, cutoff} (O(small)).
// ---------------------------------------------------------------------------
__global__ __launch_bounds__(256) void iou_k(
    const float* __restrict__ anchors, const float* __restrict__ gtb,
    unsigned long long* __restrict__ pk,
    int* __restrict__ ghist, int* __restrict__ counts,
    unsigned long long* __restrict__ gmax,
    int* __restrict__ cbR, int* __restrict__ targets,
    int* __restrict__ tickets, KeyParams kp) {
  __shared__ float4 gbox[2 * G_];               // gt boxes, duplicated
  __shared__ float  garea[2 * G_];              // gt areas, duplicated
  __shared__ unsigned long long slot2[2 * G_];  // per-(block,g residue) max pack
  __shared__ int red[256];
  __shared__ int sup[16];
  __shared__ int last;

  const int bid = blockIdx.x;
  const int t = threadIdx.x;
  const int b  = bid / NPB;
  const int xb = bid % NPB;
  const int a  = xb * 256 + t;                   // < A_ exactly
  const size_t idx = (size_t)b * A_ + a;

  // ========== body: IoU + labels + PRNG + hist + counts ===================
  {
    if (t < G_) {
      float4 gg = ((const float4*)gtb)[b * G_ + t];
      gbox[t] = gg; gbox[t + G_] = gg;
      float ag = area_of(gg.x, gg.y, gg.z, gg.w);
      garea[t] = ag; garea[t + G_] = ag;
    }
    slot2[t] = 0ull;                             // covers all 256 residues
    __syncthreads();

    float4 an = ((const float4*)anchors)[a];
    float area_a = area_of(an.x, an.y, an.z, an.w);
    const int t7 = t & (G_ - 1);
    const unsigned long long alow = (unsigned long long)(~(uint32_t)a);
    unsigned long long blp = 0ull;               // (q_bits<<32 | g^127) max
#pragma unroll 4
    for (int s = 0; s < G_; s++) {
      const int gi = t7 + s;                     // in [0, 254]; g = gi & 127
      float4 gg = gbox[gi];
      float ag  = garea[gi];
      float q;
      {
#pragma clang fp contract(off)
        float ltx = fmaxf(an.x, gg.x), lty = fmaxf(an.y, gg.y);
        float rbx = fminf(an.z, gg.z), rby = fminf(an.w, gg.w);
        float w = rbx - ltx; w = (w < 0.f) ? 0.f : w;
        float h = rby - lty; h = (h < 0.f) ? 0.f : h;
        float inter = w * h;
        float denom = area_a + ag - inter + 1e-6f;
        float r0 = __builtin_amdgcn_rcpf(denom);
        float r1 = r0 * __builtin_fmaf(-denom, r0, 2.0f);   // 1 Newton step
        q = inter * r1;                                      // ~1.5 ulp (r15 ok)
      }
      unsigned long long hi = (unsigned long long)__float_as_uint(q) << 32;
      unsigned long long lp = hi | (unsigned)((gi & (G_ - 1)) ^ (G_ - 1));
      if (lp > blp) blp = lp;                    // (higher iou, then smaller g)
      atomicMax(&slot2[gi], hi | alow);          // fire-and-forget, lanes distinct
    }
    __syncthreads();
    if (t < G_) {
      unsigned long long p = slot2[t];
      unsigned long long q2 = slot2[t + G_];
      if (q2 > p) p = q2;
      atomicMax(&gmax[b * G_ + t], p);           // once per (block, g)
    }

    float bv = __uint_as_float((uint32_t)(blp >> 32));
    int   bi = ((int)(blp & (unsigned long long)(G_ - 1))) ^ (G_ - 1);
    int lb = (bv < 0.3f) ? 0 : ((bv >= 0.7f) ? 1 : -1);
    // only the threefry stream downstream needs: vp if lb!=0, vn if lb==0
    uint32_t kk0 = (lb == 0) ? kp.k[b][2] : kp.k[b][0];
    uint32_t kk1 = (lb == 0) ? kp.k[b][3] : kp.k[b][1];
    uint32_t vv = anchor_vbits(kk0, kk1, a);
    unsigned long long pack = (unsigned long long)vv
                            | ((unsigned long long)(uint32_t)bi << 23)
                            | ((unsigned long long)(uint32_t)(lb + 1) << 30);
    st_agent_u64(&pk[idx], pack);                // LLC-direct (tail RMWs it)
    if (lb == 1)      atomicAdd(&ghist[(b * 2 + 0) * NBUCK + (vv >> BSHIFT)], 1);
    else if (lb == 0) atomicAdd(&ghist[(b * 2 + 1) * NBUCK + (vv >> BSHIFT)], 1);
    // wave-ballot counts: 4 waves x 2 atomics per block
    unsigned long long mpos = __ballot(lb == 1);
    unsigned long long mneg = __ballot(lb == 0);
    if ((t & 63) == 0) {
      if (mpos) atomicAdd(&counts[b * 2 + 0], __popcll(mpos));
      if (mneg) atomicAdd(&counts[b * 2 + 1], __popcll(mneg));
    }
  }

  // ---- per-image ticket: syncthreads drains vmcnt (stores acked at LLC) --
  __syncthreads();
  if (t == 0) {
    int v = __hip_atomic_fetch_add(&tickets[b], 1, __ATOMIC_RELAXED,
                                   __HIP_MEMORY_SCOPE_AGENT);
    last = (v == NPB - 1);
  }
  __syncthreads();
  if (!last) return;

  // ========== tail: force best anchor per gt (<=128 RMWs) =================
  if (t < G_) {
    unsigned long long gm = ld_agent_u64(&gmax[b * G_ + t]);
    int fa = (int)(~(uint32_t)(gm & 0xFFFFFFFFull));
    size_t fidx = (size_t)b * A_ + fa;
    unsigned long long old = atomicOr(&pk[fidx], 1ull << 63);
    if (!(old >> 63)) {                          // first forcer of this anchor
      int oldlb = (int)((old >> 30) & 3) - 1;
      if (oldlb != 1) {
        atomicAdd(&counts[b * 2 + 0], 1);
        // v-field already vp for oldlb==-1; recompute only for oldlb==0
        uint32_t vpf = (oldlb == -1) ? (uint32_t)(old & VMASK)
                                     : anchor_vbits(kp.k[b][0], kp.k[b][1], fa);
        atomicAdd(&ghist[(b * 2 + 0) * NBUCK + (vpf >> BSHIFT)], 1);
        if (oldlb == 0) {
          atomicSub(&counts[b * 2 + 1], 1);
          atomicSub(&ghist[(b * 2 + 1) * NBUCK + ((uint32_t)(old & VMASK) >> BSHIFT)], 1);
          st_agent_u64(&pk[fidx], (old & ~(unsigned long long)VMASK)
                                  | vpf | (1ull << 63));
        }
      }
    }
  }
  __syncthreads();   // drain force atomics before counts/ghist reads

  // ========== tail: cutoff bucket + remainder (2 rows) ====================
  {
    int npos = ld_agent_i32(&counts[b * 2 + 0]);
    int nneg = ld_agent_i32(&counts[b * 2 + 1]);
    int tp = npos < 128 ? npos : 128;
    int tn = 256 - tp; if (nneg < tn) tn = nneg;
    for (int c = 0; c < 2; ++c) {
      const int row = b * 2 + c;
      const int target = (c == 0) ? tp : tn;
      const int* hist = ghist + (size_t)row * NBUCK;
      { int s = 0; const int base = t * 4;
        for (int i = 0; i < 4; i++) s += ld_agent_i32(&hist[base + i]);
        red[t] = s; }
      __syncthreads();
      if (t < 16) { int ss = 0; for (int j = 0; j < 16; j++) ss += red[t * 16 + j]; sup[t] = ss; }
      __syncthreads();
      if (t == 0) {
        int cb = INT_MAX, R = 0;
        if (target > 0) {
          int cum = 0, si = 0;
          for (int i = 15; i >= 0; i--) { if (cum + sup[i] >= target) { si = i; break; } cum += sup[i]; }
          int sj = si * 16;
          for (int j = si * 16 + 15; j >= si * 16; j--) { if (cum + red[j] >= target) { sj = j; break; } cum += red[j]; }
          for (int k = sj * 4 + 3; k >= sj * 4; k--) {
            int hv = ld_agent_i32(&hist[k]);
            if (cum + hv >= target) { cb = k; R = target - cum; break; }
            cum += hv;
          }
        }
        st_agent_i32(&cbR[row * 2 + 0], cb);
        st_agent_i32(&cbR[row * 2 + 1], R);
        st_agent_i32(&targets[row], target);
      }
      __syncthreads();
    }
  }
}

// ---------------------------------------------------------------------------
// K2: grid-wide pack scan (cand + sure-kept loss); per-image LDS rank tail;
//     8-arrival final combine. (r14-proven shape, 1 load/anchor now.)
// ---------------------------------------------------------------------------
__global__ __launch_bounds__(256) void loss2_k(
    const float* __restrict__ anchors, const float* __restrict__ gtb,
    const float* __restrict__ cls, const float* __restrict__ boxp,
    const unsigned long long* __restrict__ pk,
    const int* __restrict__ cbR, const int* __restrict__ targets,
    int* __restrict__ ccnt, uint32_t* __restrict__ cvv, int* __restrict__ cii,
    float* __restrict__ bsums, int* __restrict__ tickets,
    float* __restrict__ out) {
  __shared__ float redf[256];
  __shared__ uint32_t scv[CCAP];
  __shared__ int sci[CCAP];
  __shared__ int last;

  const int bid = blockIdx.x;
  const int t = threadIdx.x;
  const int b  = bid / NPB;
  const int xb = bid % NPB;
  const int a  = xb * 256 + t;
  const size_t idx = (size_t)b * A_ + a;

  // ========== grid-wide: cand append + sure-kept loss =====================
  {
    float sb = 0.f, ss = 0.f;
    unsigned long long p = pk[idx];              // plain: dispatch-boundary flushed
    int lb = (int)((p >> 30) & 3) - 1;
    bool forced = (p >> 63) != 0;
    bool pos = forced || (lb == 1);
    bool neg = !pos && (lb == 0);
    if (pos || neg) {
      int c = pos ? 0 : 1;
      int row = b * 2 + c;
      uint32_t v = (uint32_t)(p & VMASK);
      int bucket = (int)(v >> BSHIFT);
      int cb = cbR[row * 2];
      if (bucket == cb) {
        int pp = atomicAdd(&ccnt[row], 1);
        if (pp < CCAP) {
          st_agent_u32(&cvv[row * CCAP + pp], v);   // tail reads cross-XCD
          st_agent_i32(&cii[row * CCAP + pp], a);
        }
      } else if (bucket > cb) {                  // sure-kept (cb==INT_MAX -> never)
        int kk = a % K_; int hw = a / K_; int hh = hw / W_; int wx = hw % W_;
        float x  = cls[(((size_t)b * K_ + kk) * H_ + hh) * W_ + wx];
        float sp = fmaxf(x, 0.f) + log1pf(expf(-fabsf(x)));   // logaddexp(x,0)
        sb = pos ? (sp - x) : sp;
        if (pos) {
          float4 an = ((const float4*)anchors)[a];
          int    mg = (int)((p >> 23) & 127);
          float4 gg = ((const float4*)gtb)[b * G_ + mg];
          float tt[4]; encode4(an, gg, tt);
          for (int cc2 = 0; cc2 < 4; cc2++) {
            float bp = boxp[(((size_t)b * (4 * K_) + (4 * kk + cc2)) * H_ + hh) * W_ + wx];
            float d = bp - tt[cc2];
            float ad = fabsf(d);
            ss += (ad < 1.f) ? (0.5f * d * d) : (ad - 0.5f);
          }
        }
      }
    }
    float sbT = block_reduce_float(sb, redf);
    float ssT = block_reduce_float(ss, redf);
    if (t == 0) {
      if (sbT != 0.f) atomicAdd(&bsums[b * 2 + 0], sbT);
      if (ssT != 0.f) atomicAdd(&bsums[b * 2 + 1], ssT);
    }
  }

  // ---- per-image ticket --------------------------------------------------
  __syncthreads();
  if (t == 0) {
    int v = __hip_atomic_fetch_add(&tickets[8 + b], 1, __ATOMIC_RELAXED,
                                   __HIP_MEMORY_SCOPE_AGENT);
    last = (v == NPB - 1);
  }
  __syncthreads();
  if (!last) return;

  // ========== tail: rank this image's 2 candidate rows (LDS-staged) =======
  for (int c = 0; c < 2; ++c) {
    const int row = b * 2 + c;
    int c2 = ld_agent_i32(&ccnt[row]); if (c2 > CCAP) c2 = CCAP;
    const int R = cbR[row * 2 + 1];
    for (int j = t; j < c2; j += 256) {
      scv[j] = ld_agent_u32(&cvv[row * CCAP + j]);
      sci[j] = ld_agent_i32(&cii[row * CCAP + j]);
    }
    __syncthreads();
    const bool pos = (c == 0);
    float sbl = 0.f, ssl = 0.f;
    for (int j = t; j < c2; j += 256) {
      uint32_t v = scv[j]; int a2 = sci[j];
      int r = 0;
      for (int k2 = 0; k2 < c2; k2++) {
        uint32_t vk = scv[k2]; int ik = sci[k2];
        if (vk > v || (vk == v && ik < a2)) r++;
      }
      if (r < R) {                                // kept: stable-rank subsample
        int kk = a2 % K_; int hw = a2 / K_; int hh = hw / W_; int wx = hw % W_;
        float x = cls[(((size_t)b * K_ + kk) * H_ + hh) * W_ + wx];
        float sp = fmaxf(x, 0.f) + log1pf(expf(-fabsf(x)));
        sbl += pos ? (sp - x) : sp;
        if (pos) {
          float4 an = ((const float4*)anchors)[a2];
          int mg = (int)((pk[(size_t)b * A_ + a2] >> 23) & 127);
          float4 gg = ((const float4*)gtb)[b * G_ + mg];
          float tt[4]; encode4(an, gg, tt);
          for (int cc2 = 0; cc2 < 4; cc2++) {
            float bp = boxp[(((size_t)b * (4 * K_) + (4 * kk + cc2)) * H_ + hh) * W_ + wx];
            float d = bp - tt[cc2];
            float ad = fabsf(d);
            ssl += (ad < 1.f) ? (0.5f * d * d) : (ad - 0.5f);
          }
        }
      }
    }
    float sbT = block_reduce_float(sbl, redf);
    float ssT = block_reduce_float(ssl, redf);
    if (t == 0) {
      if (sbT != 0.f) atomicAdd(&bsums[b * 2 + 0], sbT);
      if (ssT != 0.f) atomicAdd(&bsums[b * 2 + 1], ssT);
    }
    __syncthreads();
  }

  // ---- final ticket: 8 arrivals, one per image tail ----------------------
  __syncthreads();   // drain bsums atomics
  if (t == 0) {
    int v = __hip_atomic_fetch_add(&tickets[16], 1, __ATOMIC_RELAXED,
                                   __HIP_MEMORY_SCOPE_AGENT);
    last = (v == B_ - 1);
  }
  __syncthreads();
  if (!last) return;

  if (t == 0) {
    float cl = 0.f, bl = 0.f;
    for (int bb = 0; bb < B_; bb++) {
      int tpv = ld_agent_i32(&targets[bb * 2 + 0]);
      int tnv = ld_agent_i32(&targets[bb * 2 + 1]);
      float s0 = ld_agent_f32(&bsums[bb * 2 + 0]);
      float s1 = ld_agent_f32(&bsums[bb * 2 + 1]);
      cl += s0 / fmaxf((float)(tpv + tnv), 1.f);
      bl += s1 / fmaxf(4.f * (float)tpv, 1.f);
    }
    cl *= 0.125f; bl *= 0.125f;
    out[0] = cl; out[1] = bl; out[2] = cl + bl;
  }
}

static void compute_keys(KeyParams& kp) {
  const uint32_t r0 = 0u, r1 = 42u;        // jax.random.key(42) -> (hi, lo)
#if PARTITIONABLE
  for (int b = 0; b < B_; b++) {
    uint32_t kb0, kb1;
    tf2x32(r0, r1, 0u, (uint32_t)b, kb0, kb1);        // split(root, 8)[b]
    uint32_t a0, a1, c0, c1;
    tf2x32(kb0, kb1, 0u, 0u, a0, a1);                 // split(key)[0] = k1
    tf2x32(kb0, kb1, 0u, 1u, c0, c1);                 // split(key)[1] = k2
    kp.k[b][0] = a0; kp.k[b][1] = a1; kp.k[b][2] = c0; kp.k[b][3] = c1;
  }
#else
  uint32_t o0[8], o1[8], flat[16];
  for (int i = 0; i < 8; i++) tf2x32(r0, r1, (uint32_t)i, (uint32_t)(8 + i), o0[i], o1[i]);
  for (int i = 0; i < 8; i++) { flat[i] = o0[i]; flat[8 + i] = o1[i]; }
  for (int b = 0; b < B_; b++) {
    uint32_t kb0 = flat[2 * b], kb1 = flat[2 * b + 1];
    uint32_t a0, b0, a1, b1;
    tf2x32(kb0, kb1, 0u, 2u, a0, b0);
    tf2x32(kb0, kb1, 1u, 3u, a1, b1);
    kp.k[b][0] = a0; kp.k[b][1] = a1; kp.k[b][2] = b0; kp.k[b][3] = b1;
  }
#endif
}

extern "C" void kernel_launch(void* const* d_in, const int* in_sizes, int n_in,
                              void* d_out, int out_size, void* d_ws, size_t ws_size,
                              hipStream_t stream) {
  const float* cls     = (const float*)d_in[0];   // [B,K,H,W]
  const float* boxp    = (const float*)d_in[1];   // [B,4K,H,W]
  const float* anchors = (const float*)d_in[2];   // [A,4]
  const float* gtb     = (const float*)d_in[3];   // [B,G,4]
  float* out = (float*)d_out;

  uint8_t* w = (uint8_t*)d_ws;
  // zeroed region [0, 74496): gmax + ghist + counts + ccnt + bsums + tickets
  unsigned long long* gmax = (unsigned long long*)w;    // B*G u64 (8 KB)
  int*      ghist   = (int*)(w + 8192);                 // 16*NBUCK ints (64 KB)
  int*      counts  = (int*)(w + 73728);                // 16 ints (pad 128)
  int*      ccnt    = (int*)(w + 73856);                // 16 ints (pad 128)
  float*    bsums   = (float*)(w + 73984);              // 16 floats (pad 128)
  int*      tickets = (int*)(w + 74112);                // 17 ints (pad 384)
  // non-zeroed region
  unsigned long long* pkb = (unsigned long long*)(w + 74496);  // B*A u64 (2.36MB)
  int*      cbR     = (int*)(pkb + (size_t)B_ * A_);    // 32
  int*      targets = cbR + 32;                         // 16
  uint32_t* cvv     = (uint32_t*)(targets + 16);        // 16*CCAP
  int*      cii     = (int*)(cvv + 16 * CCAP);          // 16*CCAP

  KeyParams kp;
  compute_keys(kp);

  (void)hipMemsetAsync(w, 0, 74496, stream);
  iou_k<<<NLAB, 256, 0, stream>>>(anchors, gtb, pkb, ghist, counts, gmax,
                                  cbR, targets, tickets, kp);
  loss2_k<<<NLAB, 256, 0, stream>>>(anchors, gtb, cls, boxp, pkb,
                                    cbR, targets, ccnt, cvv, cii,
                                    bsums, tickets, out);
}